// Round 1
// baseline (293.468 us; speedup 1.0000x reference)
//
#include <hip/hip_runtime.h>

// Net_18966575579675: 722 independent tiny MLPs (11->10->10->6), B=8192, fp32.
// Strategy: thread = batch row b; loop over networks n (wave-uniform index so
// weight loads scalarize to s_load); process n in pairs so the 12 output
// floats per thread form one 48B contiguous 16B-aligned run (3x dwordx4).

#define BB 8192
#define NN 722
#define CAMD 10
#define HD 10
#define LODD 6
#define NCHUNK 16   // networks per block (must be even)

__device__ __forceinline__ void mlp_one(
    const float p, const float* __restrict__ c,
    const float* __restrict__ w1, const float* __restrict__ b1,
    const float* __restrict__ w2, const float* __restrict__ b2,
    const float* __restrict__ w3, const float* __restrict__ b3,
    float* __restrict__ o)
{
    float h1[HD];
#pragma unroll
    for (int j = 0; j < HD; ++j) {
        float a = b1[j] + p * w1[j];          // w1 row 0 is the prior_lod input
#pragma unroll
        for (int i = 0; i < CAMD; ++i)
            a = fmaf(c[i], w1[(i + 1) * HD + j], a);
        h1[j] = fmaxf(a, 0.0f);
    }
    float h2[HD];
#pragma unroll
    for (int k = 0; k < HD; ++k) {
        float a = b2[k];
#pragma unroll
        for (int j = 0; j < HD; ++j)
            a = fmaf(h1[j], w2[j * HD + k], a);
        h2[k] = fmaxf(a, 0.0f);
    }
#pragma unroll
    for (int m = 0; m < LODD; ++m) {
        float a = b3[m];
#pragma unroll
        for (int j = 0; j < HD; ++j)
            a = fmaf(h2[j], w3[j * LODD + m], a);
        o[m] = a;
    }
}

__global__ __launch_bounds__(256) void Net_18966575579675_kernel(
    const float* __restrict__ prior, const float* __restrict__ camera,
    const float* __restrict__ W1, const float* __restrict__ b1,
    const float* __restrict__ W2, const float* __restrict__ b2,
    const float* __restrict__ W3, const float* __restrict__ b3,
    float* __restrict__ out)
{
    const int b = blockIdx.x * 256 + threadIdx.x;
    const int n_start = blockIdx.y * NCHUNK;
    const int n_end = (n_start + NCHUNK < NN) ? (n_start + NCHUNK) : NN;

    // camera[b, 0:10] -> registers (8B vector loads; base 40*b is 8-aligned)
    float c[CAMD];
    const float2* cam2 = (const float2*)(camera + (size_t)b * CAMD);
#pragma unroll
    for (int i = 0; i < CAMD / 2; ++i) {
        float2 v = cam2[i];
        c[2 * i]     = v.x;
        c[2 * i + 1] = v.y;
    }

    for (int n0 = n_start; n0 < n_end; n0 += 2) {
        // prior_lod[b, n0:n0+2]  ((b*722+n0) even -> 8-aligned)
        float2 p2 = *(const float2*)(prior + (size_t)b * NN + n0);

        float o[12];
        mlp_one(p2.x, c,
                W1 + (size_t)n0 * (CAMD + 1) * HD, b1 + (size_t)n0 * HD,
                W2 + (size_t)n0 * HD * HD,         b2 + (size_t)n0 * HD,
                W3 + (size_t)n0 * HD * LODD,       b3 + (size_t)n0 * LODD,
                o);
        const int n1 = n0 + 1;
        mlp_one(p2.y, c,
                W1 + (size_t)n1 * (CAMD + 1) * HD, b1 + (size_t)n1 * HD,
                W2 + (size_t)n1 * HD * HD,         b2 + (size_t)n1 * HD,
                W3 + (size_t)n1 * HD * LODD,       b3 + (size_t)n1 * LODD,
                o + 6);

        // out[b, n0, 0] .. out[b, n1, 5]: 12 contiguous floats, 16B-aligned
        float4* o4 = (float4*)(out + (size_t)b * (NN * LODD) + (size_t)n0 * LODD);
        o4[0] = make_float4(o[0], o[1], o[2], o[3]);
        o4[1] = make_float4(o[4], o[5], o[6], o[7]);
        o4[2] = make_float4(o[8], o[9], o[10], o[11]);
    }
}

extern "C" void kernel_launch(void* const* d_in, const int* in_sizes, int n_in,
                              void* d_out, int out_size, void* d_ws, size_t ws_size,
                              hipStream_t stream) {
    const float* prior  = (const float*)d_in[0];
    const float* camera = (const float*)d_in[1];
    const float* W1     = (const float*)d_in[2];
    const float* b1     = (const float*)d_in[3];
    const float* W2     = (const float*)d_in[4];
    const float* b2     = (const float*)d_in[5];
    const float* W3     = (const float*)d_in[6];
    const float* b3     = (const float*)d_in[7];
    float* out = (float*)d_out;

    dim3 grid(BB / 256, (NN + NCHUNK - 1) / NCHUNK);
    dim3 block(256);
    Net_18966575579675_kernel<<<grid, block, 0, stream>>>(
        prior, camera, W1, b1, W2, b2, W3, b3, out);
}

// Round 2
// 285.389 us; speedup vs baseline: 1.0283x; 1.0283x over previous
//
#include <hip/hip_runtime.h>

// Net_18966575579675: 722 tiny MLPs (11->10->10->6), B=8192, fp32.
// R2: keep lane=b (wave-uniform n -> s_load weights into SGPRs), add LDS
// transpose so global stores are coalesced float4 runs along each out row.
// Block = 256 thr = 4 waves x 64 b-rows. Per chunk, wave w computes n-pair
// (chunk*4 + w) for its 64 b's -> 12 floats/lane -> LDS[64][49-pad] ->
// block-wide flush: 64 rows x 192B contiguous aligned float4 stores.

#define NN 722
#define NPAIRS 361          // 722/2
#define CAMD 10
#define HD 10
#define LODD 6
#define ROWF (NN * LODD)    // 4332 floats per output row
#define BT 64               // batch rows per block
#define NCHUNKS 91          // ceil(361 pairs / 4 pairs-per-chunk)
#define CPG 7               // chunks per group (13 * 7 = 91)
#define NGROUPS 13
#define LSTRIDE 49          // 48 floats + 1 pad (49 odd -> conflict-free)

__device__ __forceinline__ void mlp_one(
    const float p, const float* __restrict__ c,
    const float* __restrict__ w1, const float* __restrict__ b1,
    const float* __restrict__ w2, const float* __restrict__ b2,
    const float* __restrict__ w3, const float* __restrict__ b3,
    float* __restrict__ o)
{
    float h1[HD];
#pragma unroll
    for (int j = 0; j < HD; ++j) {
        float a = b1[j] + p * w1[j];          // W1 row 0 multiplies prior_lod
#pragma unroll
        for (int i = 0; i < CAMD; ++i)
            a = fmaf(c[i], w1[(i + 1) * HD + j], a);
        h1[j] = fmaxf(a, 0.0f);
    }
    float h2[HD];
#pragma unroll
    for (int k = 0; k < HD; ++k) {
        float a = b2[k];
#pragma unroll
        for (int j = 0; j < HD; ++j)
            a = fmaf(h1[j], w2[j * HD + k], a);
        h2[k] = fmaxf(a, 0.0f);
    }
#pragma unroll
    for (int m = 0; m < LODD; ++m) {
        float a = b3[m];
#pragma unroll
        for (int j = 0; j < HD; ++j)
            a = fmaf(h2[j], w3[j * LODD + m], a);
        o[m] = a;
    }
}

__global__ __launch_bounds__(256) void Net_18966575579675_kernel(
    const float* __restrict__ prior, const float* __restrict__ camera,
    const float* __restrict__ W1, const float* __restrict__ b1,
    const float* __restrict__ W2, const float* __restrict__ b2,
    const float* __restrict__ W3, const float* __restrict__ b3,
    float* __restrict__ out)
{
    const int tid  = threadIdx.x;
    const int lane = tid & 63;
    // readfirstlane forces the compiler to treat the wave id (and thus all
    // weight addresses) as wave-uniform -> s_load (SMEM) weight fetches.
    const int wave = __builtin_amdgcn_readfirstlane(tid >> 6);
    const int b0   = blockIdx.x * BT;
    const int b    = b0 + lane;

    const int c_begin = blockIdx.y * CPG;
    const int c_end   = (c_begin + CPG < NCHUNKS) ? (c_begin + CPG) : NCHUNKS;

    __shared__ float lds[BT * LSTRIDE];   // 12544 B

    // camera[b, 0:10] -> registers (8B loads, 8-aligned since 40*b)
    float cam[CAMD];
    const float2* cam2 = (const float2*)(camera + (size_t)b * CAMD);
#pragma unroll
    for (int i = 0; i < CAMD / 2; ++i) {
        float2 v = cam2[i];
        cam[2 * i]     = v.x;
        cam[2 * i + 1] = v.y;
    }

    for (int c = c_begin; c < c_end; ++c) {
        const int p = c * 4 + wave;       // wave-uniform pair index
        if (p < NPAIRS) {
            const int n0 = 2 * p;
            const float2 pr = *(const float2*)(prior + (size_t)b * NN + n0);
            float o[12];
            mlp_one(pr.x, cam,
                    W1 + (size_t)n0 * 110, b1 + (size_t)n0 * 10,
                    W2 + (size_t)n0 * 100, b2 + (size_t)n0 * 10,
                    W3 + (size_t)n0 * 60,  b3 + (size_t)n0 * 6, o);
            const int n1 = n0 + 1;
            mlp_one(pr.y, cam,
                    W1 + (size_t)n1 * 110, b1 + (size_t)n1 * 10,
                    W2 + (size_t)n1 * 100, b2 + (size_t)n1 * 10,
                    W3 + (size_t)n1 * 60,  b3 + (size_t)n1 * 6, o + 6);
            // lane -> row, wave -> 12-float column slot. Stride 49 (odd):
            // banks (49*lane + k) % 32 distinct over 32 lanes, 2-way over 64.
#pragma unroll
            for (int j = 0; j < 12; ++j)
                lds[lane * LSTRIDE + wave * 12 + j] = o[j];
        }
        __syncthreads();

        const int rem = NPAIRS - c * 4;
        const int nfp = rem < 4 ? rem : 4;       // valid pairs this chunk
        if (nfp == 4) {
            // 64 rows x 48 floats = 768 float4 -> 3 per thread, consecutive
            // lanes cover consecutive float4 within each 192B row segment.
#pragma unroll
            for (int k = 0; k < 3; ++k) {
                const int f   = k * 256 + tid;
                const int row = f / 12;
                const int col = f % 12;
                const float* s = lds + row * LSTRIDE + col * 4;
                float4 v = make_float4(s[0], s[1], s[2], s[3]);
                // float index = (b0+row)*4332 + c*48 + col*4 : all %4==0 -> 16B aligned
                *(float4*)(out + (size_t)(b0 + row) * ROWF + c * 48 + col * 4) = v;
            }
        } else {
            // tail chunk (only chunk 90, nfp==1)
            const int ncol = nfp * 3;
            const int total = BT * ncol;
            for (int f = tid; f < total; f += 256) {
                const int row = f / ncol;
                const int col = f - row * ncol;
                const float* s = lds + row * LSTRIDE + col * 4;
                float4 v = make_float4(s[0], s[1], s[2], s[3]);
                *(float4*)(out + (size_t)(b0 + row) * ROWF + c * 48 + col * 4) = v;
            }
        }
        __syncthreads();
    }
}

extern "C" void kernel_launch(void* const* d_in, const int* in_sizes, int n_in,
                              void* d_out, int out_size, void* d_ws, size_t ws_size,
                              hipStream_t stream) {
    const float* prior  = (const float*)d_in[0];
    const float* camera = (const float*)d_in[1];
    const float* W1     = (const float*)d_in[2];
    const float* b1     = (const float*)d_in[3];
    const float* W2     = (const float*)d_in[4];
    const float* b2     = (const float*)d_in[5];
    const float* W3     = (const float*)d_in[6];
    const float* b3     = (const float*)d_in[7];
    float* out = (float*)d_out;

    dim3 grid(8192 / BT, NGROUPS);   // 128 x 13 = 1664 blocks
    dim3 block(256);
    Net_18966575579675_kernel<<<grid, block, 0, stream>>>(
        prior, camera, W1, b1, W2, b2, W3, b3, out);
}

// Round 3
// 268.996 us; speedup vs baseline: 1.0910x; 1.0609x over previous
//
#include <hip/hip_runtime.h>

// Net_18966575579675: 722 tiny MLPs (11->10->10->6), B=8192, fp32.
// R3: amortize scalar (SGPR) weight loads over SUB=4 batch sub-tiles.
// Block = 256 thr = 4 waves; each wave handles ONE net per chunk for
// 4x64=256 batch rows. Weight rows (10 floats, contiguous -> s_load) are
// each reused by 40 FMAs, hiding SMEM latency. Outputs go through an LDS
// transpose so global stores are contiguous aligned float4 runs.

#define NN 722
#define CAMD 10
#define HD 10
#define LODD 6
#define ROWF (NN * LODD)       // 4332 floats per output row
#define SUB 4                  // batch sub-tiles per wave
#define BT 256                 // batch rows per block (SUB*64)
#define NETS_PER_CHUNK 4       // one net per wave
#define NCHUNKS 181            // ceil(722/4); last chunk has 2 nets
#define CPG 6                  // chunks per y-group
#define NGROUPS 31             // 30*6=180 full chunks + 1 tail chunk
#define LSTRIDE 25             // 24 floats + 1 pad (odd -> conflict-free)

__global__ __launch_bounds__(256) void Net_18966575579675_kernel(
    const float* __restrict__ prior, const float* __restrict__ camera,
    const float* __restrict__ W1, const float* __restrict__ b1,
    const float* __restrict__ W2, const float* __restrict__ b2,
    const float* __restrict__ W3, const float* __restrict__ b3,
    float* __restrict__ out)
{
    const int tid  = threadIdx.x;
    const int lane = tid & 63;
    // Force wave id (hence net index / all weight addresses) wave-uniform
    // so weight fetches scalarize to s_load.
    const int wave = __builtin_amdgcn_readfirstlane(tid >> 6);
    const int b0   = blockIdx.x * BT;

    const int c_begin = blockIdx.y * CPG;
    const int c_end   = (c_begin + CPG < NCHUNKS) ? (c_begin + CPG) : NCHUNKS;

    __shared__ float lds[BT * LSTRIDE];   // 25600 B

    // camera for all 4 sub-tiles -> registers (8B aligned float2 loads)
    float cam[SUB][CAMD];
#pragma unroll
    for (int s = 0; s < SUB; ++s) {
        const float2* cam2 = (const float2*)(camera + (size_t)(b0 + s * 64 + lane) * CAMD);
#pragma unroll
        for (int i = 0; i < CAMD / 2; ++i) {
            float2 v = cam2[i];
            cam[s][2 * i]     = v.x;
            cam[s][2 * i + 1] = v.y;
        }
    }

    for (int c = c_begin; c < c_end; ++c) {
        const int n = c * NETS_PER_CHUNK + wave;   // wave-uniform net index
        if (n < NN) {
            const float* __restrict__ w1 = W1 + (size_t)n * (CAMD + 1) * HD;
            const float* __restrict__ p1 = b1 + (size_t)n * HD;
            const float* __restrict__ w2 = W2 + (size_t)n * HD * HD;
            const float* __restrict__ p2 = b2 + (size_t)n * HD;
            const float* __restrict__ w3 = W3 + (size_t)n * HD * LODD;
            const float* __restrict__ p3 = b3 + (size_t)n * LODD;

            float pr[SUB];
#pragma unroll
            for (int s = 0; s < SUB; ++s)
                pr[s] = prior[(size_t)(b0 + s * 64 + lane) * NN + n];

            // ---- layer 1: h1 = relu(x @ W1 + b1), x = [prior, cam] ----
            float h1[SUB][HD];
#pragma unroll
            for (int j = 0; j < HD; ++j) {
                const float bj = p1[j];
                const float w  = w1[j];              // W1 row 0 (prior input)
#pragma unroll
                for (int s = 0; s < SUB; ++s)
                    h1[s][j] = fmaf(pr[s], w, bj);
            }
#pragma unroll
            for (int i = 0; i < CAMD; ++i) {
#pragma unroll
                for (int j = 0; j < HD; ++j) {
                    const float w = w1[(i + 1) * HD + j];   // row-major: contiguous s_loads
#pragma unroll
                    for (int s = 0; s < SUB; ++s)
                        h1[s][j] = fmaf(cam[s][i], w, h1[s][j]);
                }
            }
#pragma unroll
            for (int s = 0; s < SUB; ++s)
#pragma unroll
                for (int j = 0; j < HD; ++j)
                    h1[s][j] = fmaxf(h1[s][j], 0.0f);

            // ---- layer 2: h2 = relu(h1 @ W2 + b2) ----
            float h2[SUB][HD];
#pragma unroll
            for (int k = 0; k < HD; ++k) {
                const float bk = p2[k];
#pragma unroll
                for (int s = 0; s < SUB; ++s)
                    h2[s][k] = bk;
            }
#pragma unroll
            for (int j = 0; j < HD; ++j) {
#pragma unroll
                for (int k = 0; k < HD; ++k) {
                    const float w = w2[j * HD + k];
#pragma unroll
                    for (int s = 0; s < SUB; ++s)
                        h2[s][k] = fmaf(h1[s][j], w, h2[s][k]);
                }
            }
#pragma unroll
            for (int s = 0; s < SUB; ++s)
#pragma unroll
                for (int k = 0; k < HD; ++k)
                    h2[s][k] = fmaxf(h2[s][k], 0.0f);

            // ---- layer 3: o = h2 @ W3 + b3 ----
            float o[SUB][LODD];
#pragma unroll
            for (int m = 0; m < LODD; ++m) {
                const float bm = p3[m];
#pragma unroll
                for (int s = 0; s < SUB; ++s)
                    o[s][m] = bm;
            }
#pragma unroll
            for (int j = 0; j < HD; ++j) {
#pragma unroll
                for (int m = 0; m < LODD; ++m) {
                    const float w = w3[j * LODD + m];
#pragma unroll
                    for (int s = 0; s < SUB; ++s)
                        o[s][m] = fmaf(h2[s][j], w, o[s][m]);
                }
            }

            // stash into LDS transpose buffer: row = b-row, col = wave*6+m
#pragma unroll
            for (int s = 0; s < SUB; ++s)
#pragma unroll
                for (int m = 0; m < LODD; ++m)
                    lds[(s * 64 + lane) * LSTRIDE + wave * LODD + m] = o[s][m];
        }
        __syncthreads();

        // flush: nv nets * 6 floats per row, 256 rows, aligned float4 runs
        const int rem  = NN - c * NETS_PER_CHUNK;
        const int nv   = rem < NETS_PER_CHUNK ? rem : NETS_PER_CHUNK;
        const int nq   = (nv * LODD) >> 2;        // float4 per row (6 or 3)
        const int tot  = BT * nq;
        for (int f = tid; f < tot; f += 256) {
            const int row  = f / nq;
            const int colq = f - row * nq;
            const float* s = lds + row * LSTRIDE + colq * 4;
            float4 v = make_float4(s[0], s[1], s[2], s[3]);
            *(float4*)(out + (size_t)(b0 + row) * ROWF + c * (NETS_PER_CHUNK * LODD) + colq * 4) = v;
        }
        __syncthreads();
    }
}

extern "C" void kernel_launch(void* const* d_in, const int* in_sizes, int n_in,
                              void* d_out, int out_size, void* d_ws, size_t ws_size,
                              hipStream_t stream) {
    const float* prior  = (const float*)d_in[0];
    const float* camera = (const float*)d_in[1];
    const float* W1     = (const float*)d_in[2];
    const float* b1     = (const float*)d_in[3];
    const float* W2     = (const float*)d_in[4];
    const float* b2     = (const float*)d_in[5];
    const float* W3     = (const float*)d_in[6];
    const float* b3     = (const float*)d_in[7];
    float* out = (float*)d_out;

    dim3 grid(8192 / BT, NGROUPS);   // 32 x 31 = 992 blocks
    dim3 block(256);
    Net_18966575579675_kernel<<<grid, block, 0, stream>>>(
        prior, camera, W1, b1, W2, b2, W3, b3, out);
}

// Round 4
// 254.516 us; speedup vs baseline: 1.1530x; 1.0569x over previous
//
#include <hip/hip_runtime.h>

// Net_18966575579675: 722 tiny MLPs (11->10->10->6), B=8192, fp32.
// R4 = R3 (SGPR-weight reuse over SUB=4 batch sub-tiles, LDS store
// transpose) with 3x more blocks: CPG 6->2, NGROUPS 31->91, grid 992->2912.
// R3 showed Occupancy=25% (grid-starved: 3.9 blocks/CU vs 6 the LDS allows)
// -> latency-bound. More resident waves is the cheapest fix.

#define NN 722
#define CAMD 10
#define HD 10
#define LODD 6
#define ROWF (NN * LODD)       // 4332 floats per output row
#define SUB 4                  // batch sub-tiles per wave
#define BT 256                 // batch rows per block (SUB*64)
#define NETS_PER_CHUNK 4       // one net per wave
#define NCHUNKS 181            // ceil(722/4); last chunk has 2 nets
#define CPG 2                  // chunks per y-group
#define NGROUPS 91             // 91*2 = 182 slots >= 181 chunks
#define LSTRIDE 25             // 24 floats + 1 pad (odd -> conflict-free)

__global__ __launch_bounds__(256) void Net_18966575579675_kernel(
    const float* __restrict__ prior, const float* __restrict__ camera,
    const float* __restrict__ W1, const float* __restrict__ b1,
    const float* __restrict__ W2, const float* __restrict__ b2,
    const float* __restrict__ W3, const float* __restrict__ b3,
    float* __restrict__ out)
{
    const int tid  = threadIdx.x;
    const int lane = tid & 63;
    // Force wave id (hence net index / all weight addresses) wave-uniform
    // so weight fetches scalarize to s_load.
    const int wave = __builtin_amdgcn_readfirstlane(tid >> 6);
    const int b0   = blockIdx.x * BT;

    const int c_begin = blockIdx.y * CPG;
    const int c_end   = (c_begin + CPG < NCHUNKS) ? (c_begin + CPG) : NCHUNKS;

    __shared__ float lds[BT * LSTRIDE];   // 25600 B

    // camera for all 4 sub-tiles -> registers (8B aligned float2 loads)
    float cam[SUB][CAMD];
#pragma unroll
    for (int s = 0; s < SUB; ++s) {
        const float2* cam2 = (const float2*)(camera + (size_t)(b0 + s * 64 + lane) * CAMD);
#pragma unroll
        for (int i = 0; i < CAMD / 2; ++i) {
            float2 v = cam2[i];
            cam[s][2 * i]     = v.x;
            cam[s][2 * i + 1] = v.y;
        }
    }

    for (int c = c_begin; c < c_end; ++c) {
        const int n = c * NETS_PER_CHUNK + wave;   // wave-uniform net index
        if (n < NN) {
            const float* __restrict__ w1 = W1 + (size_t)n * (CAMD + 1) * HD;
            const float* __restrict__ p1 = b1 + (size_t)n * HD;
            const float* __restrict__ w2 = W2 + (size_t)n * HD * HD;
            const float* __restrict__ p2 = b2 + (size_t)n * HD;
            const float* __restrict__ w3 = W3 + (size_t)n * HD * LODD;
            const float* __restrict__ p3 = b3 + (size_t)n * LODD;

            float pr[SUB];
#pragma unroll
            for (int s = 0; s < SUB; ++s)
                pr[s] = prior[(size_t)(b0 + s * 64 + lane) * NN + n];

            // ---- layer 1: h1 = relu(x @ W1 + b1), x = [prior, cam] ----
            float h1[SUB][HD];
#pragma unroll
            for (int j = 0; j < HD; ++j) {
                const float bj = p1[j];
                const float w  = w1[j];              // W1 row 0 (prior input)
#pragma unroll
                for (int s = 0; s < SUB; ++s)
                    h1[s][j] = fmaf(pr[s], w, bj);
            }
#pragma unroll
            for (int i = 0; i < CAMD; ++i) {
#pragma unroll
                for (int j = 0; j < HD; ++j) {
                    const float w = w1[(i + 1) * HD + j];   // contiguous s_loads
#pragma unroll
                    for (int s = 0; s < SUB; ++s)
                        h1[s][j] = fmaf(cam[s][i], w, h1[s][j]);
                }
            }
#pragma unroll
            for (int s = 0; s < SUB; ++s)
#pragma unroll
                for (int j = 0; j < HD; ++j)
                    h1[s][j] = fmaxf(h1[s][j], 0.0f);

            // ---- layer 2: h2 = relu(h1 @ W2 + b2) ----
            float h2[SUB][HD];
#pragma unroll
            for (int k = 0; k < HD; ++k) {
                const float bk = p2[k];
#pragma unroll
                for (int s = 0; s < SUB; ++s)
                    h2[s][k] = bk;
            }
#pragma unroll
            for (int j = 0; j < HD; ++j) {
#pragma unroll
                for (int k = 0; k < HD; ++k) {
                    const float w = w2[j * HD + k];
#pragma unroll
                    for (int s = 0; s < SUB; ++s)
                        h2[s][k] = fmaf(h1[s][j], w, h2[s][k]);
                }
            }
#pragma unroll
            for (int s = 0; s < SUB; ++s)
#pragma unroll
                for (int k = 0; k < HD; ++k)
                    h2[s][k] = fmaxf(h2[s][k], 0.0f);

            // ---- layer 3: o = h2 @ W3 + b3 ----
            float o[SUB][LODD];
#pragma unroll
            for (int m = 0; m < LODD; ++m) {
                const float bm = p3[m];
#pragma unroll
                for (int s = 0; s < SUB; ++s)
                    o[s][m] = bm;
            }
#pragma unroll
            for (int j = 0; j < HD; ++j) {
#pragma unroll
                for (int m = 0; m < LODD; ++m) {
                    const float w = w3[j * LODD + m];
#pragma unroll
                    for (int s = 0; s < SUB; ++s)
                        o[s][m] = fmaf(h2[s][j], w, o[s][m]);
                }
            }

            // stash into LDS transpose buffer: row = b-row, col = wave*6+m
#pragma unroll
            for (int s = 0; s < SUB; ++s)
#pragma unroll
                for (int m = 0; m < LODD; ++m)
                    lds[(s * 64 + lane) * LSTRIDE + wave * LODD + m] = o[s][m];
        }
        __syncthreads();

        // flush: nv nets * 6 floats per row, 256 rows, aligned float4 runs
        const int rem  = NN - c * NETS_PER_CHUNK;
        const int nv   = rem < NETS_PER_CHUNK ? rem : NETS_PER_CHUNK;
        const int nq   = (nv * LODD) >> 2;        // float4 per row (6 or 3)
        const int tot  = BT * nq;
        for (int f = tid; f < tot; f += 256) {
            const int row  = f / nq;
            const int colq = f - row * nq;
            const float* s = lds + row * LSTRIDE + colq * 4;
            float4 v = make_float4(s[0], s[1], s[2], s[3]);
            *(float4*)(out + (size_t)(b0 + row) * ROWF + c * (NETS_PER_CHUNK * LODD) + colq * 4) = v;
        }
        __syncthreads();
    }
}

extern "C" void kernel_launch(void* const* d_in, const int* in_sizes, int n_in,
                              void* d_out, int out_size, void* d_ws, size_t ws_size,
                              hipStream_t stream) {
    const float* prior  = (const float*)d_in[0];
    const float* camera = (const float*)d_in[1];
    const float* W1     = (const float*)d_in[2];
    const float* b1     = (const float*)d_in[3];
    const float* W2     = (const float*)d_in[4];
    const float* b2     = (const float*)d_in[5];
    const float* W3     = (const float*)d_in[6];
    const float* b3     = (const float*)d_in[7];
    float* out = (float*)d_out;

    dim3 grid(8192 / BT, NGROUPS);   // 32 x 91 = 2912 blocks (~11/CU)
    dim3 block(256);
    Net_18966575579675_kernel<<<grid, block, 0, stream>>>(
        prior, camera, W1, b1, W2, b2, W3, b3, out);
}